// Round 1
// baseline (1574.550 us; speedup 1.0000x reference)
//
#include <hip/hip_runtime.h>
#include <math.h>

// Problem constants (from reference setup_inputs)
#define B     256     // queries
#define KD    128     // key dim
#define VD    128     // value dim
#define TOPK  8
#define NB    512     // candidate blocks over the key axis
#define KB    16      // keys staged per LDS tile in k_cand

__device__ __forceinline__ float dot4(float4 a, float4 b) {
    return a.x * b.x + a.y * b.y + a.z * b.z + a.w * b.w;
}

// (score, index) ordering with lax.top_k tie-break (lower index wins on ties)
__device__ __forceinline__ bool gt_si(float a, int ai, float b, int bi) {
    return (a > b) || (a == b && ai < bi);
}

// ---------------------------------------------------------------------------
// Kernel 1: L2-normalize query rows.  grid=B, block=64 (one wave per row).
// ---------------------------------------------------------------------------
__global__ __launch_bounds__(64) void k_norm_q(const float* __restrict__ q,
                                               float* __restrict__ qn) {
    const int row = blockIdx.x;
    const int t   = threadIdx.x;
    const float2* src = (const float2*)(q + (size_t)row * KD);
    float2 v = src[t];                       // 64 lanes x 2 = 128 elems
    float ss = v.x * v.x + v.y * v.y;
#pragma unroll
    for (int m = 32; m >= 1; m >>= 1) ss += __shfl_xor(ss, m);
    const float inv = 1.0f / fmaxf(sqrtf(ss), 1e-12f);
    float2 o; o.x = v.x * inv; o.y = v.y * inv;
    ((float2*)(qn + (size_t)row * KD))[t] = o;
}

// ---------------------------------------------------------------------------
// Kernel 2: per-block candidate top-8.
// grid=NB, block=256.  Thread t <-> query t (q-row in 128 VGPRs).
// Block b scans keys [b*chunk, min(N,(b+1)*chunk)).
// Keys staged into LDS pre-normalized (row norm via 16-lane shfl reduce).
// ---------------------------------------------------------------------------
__global__ __launch_bounds__(256, 2) void k_cand(const float* __restrict__ keys,
                                                 const float* __restrict__ qn,
                                                 float* __restrict__ cand_s,
                                                 int* __restrict__ cand_i,
                                                 int N, int chunk) {
    __shared__ float lk[KB][KD];             // 8 KiB

    const int t    = threadIdx.x;
    const int b    = blockIdx.x;
    const int base = b * chunk;
    const int nend = min(N, base + chunk);

    // Query row t in registers (32 x float4 = 128 VGPRs).
    float4 qv[KD / 4];
    {
        const float4* qrow = (const float4*)(qn + (size_t)t * KD);
#pragma unroll
        for (int i = 0; i < KD / 4; ++i) qv[i] = qrow[i];
    }

    float s[TOPK];
    int   id[TOPK];
#pragma unroll
    for (int j = 0; j < TOPK; ++j) { s[j] = -1e30f; id[j] = 0; }

    const int jrow = t >> 4;   // which of the KB staged keys this thread loads
    const int seg  = t & 15;   // 8-float segment within the key row

    for (int g = base; g < nend; g += KB) {
        // ---- stage KB normalized key rows into LDS ----
        const int row = g + jrow;
        float4 a, c;
        if (row < nend) {
            const float4* kr = (const float4*)(keys + (size_t)row * KD + seg * 8);
            a = kr[0];
            c = kr[1];
        } else {
            a = make_float4(0.f, 0.f, 0.f, 0.f);
            c = a;
        }
        float ss = a.x * a.x + a.y * a.y + a.z * a.z + a.w * a.w
                 + c.x * c.x + c.y * c.y + c.z * c.z + c.w * c.w;
#pragma unroll
        for (int m = 8; m >= 1; m >>= 1) ss += __shfl_xor(ss, m);  // 16-lane group
        const float inv = 1.0f / fmaxf(sqrtf(ss), 1e-12f);
        a.x *= inv; a.y *= inv; a.z *= inv; a.w *= inv;
        c.x *= inv; c.y *= inv; c.z *= inv; c.w *= inv;
        float4* dst = (float4*)&lk[jrow][seg * 8];
        dst[0] = a;
        dst[1] = c;
        __syncthreads();

        // ---- dot each staged key against this thread's query ----
        const int kmax = min(KB, nend - g);
        for (int j = 0; j < kmax; ++j) {
            const float4* kr4 = (const float4*)&lk[j][0];
            float d0 = 0.f, d1 = 0.f, d2 = 0.f, d3 = 0.f;
#pragma unroll
            for (int i = 0; i < KD / 4; i += 4) {
                d0 += dot4(qv[i + 0], kr4[i + 0]);
                d1 += dot4(qv[i + 1], kr4[i + 1]);
                d2 += dot4(qv[i + 2], kr4[i + 2]);
                d3 += dot4(qv[i + 3], kr4[i + 3]);
            }
            const float sim = (d0 + d1) + (d2 + d3);
            const int kidx = g + j;
            if (sim > s[TOPK - 1]) {          // strict > : lower index wins ties
                s[TOPK - 1]  = sim;
                id[TOPK - 1] = kidx;
#pragma unroll
                for (int u = TOPK - 1; u >= 1; --u) {
                    const bool sw = s[u] > s[u - 1];
                    if (sw) {
                        float ts = s[u]; s[u] = s[u - 1]; s[u - 1] = ts;
                        int   ti = id[u]; id[u] = id[u - 1]; id[u - 1] = ti;
                    }
                }
            }
        }
        __syncthreads();
    }

    // ---- emit per-block candidates ----
    float* os = cand_s + ((size_t)b * B + t) * TOPK;
    int*   oi = cand_i + ((size_t)b * B + t) * TOPK;
#pragma unroll
    for (int j = 0; j < TOPK; ++j) { os[j] = s[j]; oi[j] = id[j]; }
}

// ---------------------------------------------------------------------------
// Kernel 3: merge NB*8 candidates per query -> final sorted top-8,
// write scores and gather value rows.  grid=B, block=64 (one wave).
// ---------------------------------------------------------------------------
__global__ __launch_bounds__(64) void k_merge(const float* __restrict__ cand_s,
                                              const int* __restrict__ cand_i,
                                              const float* __restrict__ values,
                                              float* __restrict__ out_slots,
                                              float* __restrict__ out_scores) {
    const int q    = blockIdx.x;
    const int lane = threadIdx.x;

    float s[TOPK];
    int   id[TOPK];
#pragma unroll
    for (int j = 0; j < TOPK; ++j) { s[j] = -1e30f; id[j] = -1; }

    // Each lane scans NB/64 blocks' candidate lists.
    for (int b = lane; b < NB; b += 64) {
        const float* cs = cand_s + ((size_t)b * B + q) * TOPK;
        const int*   ci = cand_i + ((size_t)b * B + q) * TOPK;
#pragma unroll
        for (int j = 0; j < TOPK; ++j) {
            const float v  = cs[j];
            const int   vi = ci[j];
            if (gt_si(v, vi, s[TOPK - 1], id[TOPK - 1])) {
                s[TOPK - 1]  = v;
                id[TOPK - 1] = vi;
#pragma unroll
                for (int u = TOPK - 1; u >= 1; --u) {
                    if (gt_si(s[u], id[u], s[u - 1], id[u - 1])) {
                        float ts = s[u]; s[u] = s[u - 1]; s[u - 1] = ts;
                        int   ti = id[u]; id[u] = id[u - 1]; id[u - 1] = ti;
                    }
                }
            }
        }
    }

    // Butterfly bitonic top-8 merge across the wave.
#pragma unroll
    for (int m = 1; m <= 32; m <<= 1) {
        float bs[TOPK]; int bi[TOPK];
#pragma unroll
        for (int j = 0; j < TOPK; ++j) {
            bs[j] = __shfl_xor(s[j], m);
            bi[j] = __shfl_xor(id[j], m);
        }
        float ms[TOPK]; int mi[TOPK];
#pragma unroll
        for (int j = 0; j < TOPK; ++j) {
            const float av = s[j];          const int ai = id[j];
            const float bv = bs[TOPK-1-j];  const int b2 = bi[TOPK-1-j];
            const bool g = gt_si(av, ai, bv, b2);
            ms[j] = g ? av : bv;
            mi[j] = g ? ai : b2;
        }
        // bitonic sort (desc) of the bitonic sequence: distances 4,2,1
#define CAS_(x, y)                                                     \
        { if (!gt_si(ms[x], mi[x], ms[y], mi[y])) {                    \
              float tv = ms[x]; ms[x] = ms[y]; ms[y] = tv;             \
              int   ti = mi[x]; mi[x] = mi[y]; mi[y] = ti; } }
        CAS_(0, 4); CAS_(1, 5); CAS_(2, 6); CAS_(3, 7);
        CAS_(0, 2); CAS_(1, 3); CAS_(4, 6); CAS_(5, 7);
        CAS_(0, 1); CAS_(2, 3); CAS_(4, 5); CAS_(6, 7);
#undef CAS_
#pragma unroll
        for (int j = 0; j < TOPK; ++j) { s[j] = ms[j]; id[j] = mi[j]; }
    }

    if (lane == 0) {
#pragma unroll
        for (int j = 0; j < TOPK; ++j) out_scores[(size_t)q * TOPK + j] = s[j];
    }

    // Gather value rows: all lanes hold identical id[]; float2 per lane.
#pragma unroll
    for (int j = 0; j < TOPK; ++j) {
        const int row = id[j];
        const float2* src = (const float2*)(values + (size_t)row * VD);
        float2 v = src[lane];
        ((float2*)(out_slots + ((size_t)q * TOPK + j) * VD))[lane] = v;
    }
}

// ---------------------------------------------------------------------------
extern "C" void kernel_launch(void* const* d_in, const int* in_sizes, int n_in,
                              void* d_out, int out_size, void* d_ws, size_t ws_size,
                              hipStream_t stream) {
    const float* q      = (const float*)d_in[0];
    const float* keys   = (const float*)d_in[1];
    const float* values = (const float*)d_in[2];
    const int N = in_sizes[1] / KD;          // 500000

    float* out_slots  = (float*)d_out;                       // B*TOPK*VD
    float* out_scores = out_slots + (size_t)B * TOPK * VD;   // B*TOPK

    // workspace layout
    float* qn     = (float*)d_ws;                            // B*KD
    float* cand_s = qn + (size_t)B * KD;                     // NB*B*TOPK
    int*   cand_i = (int*)(cand_s + (size_t)NB * B * TOPK);  // NB*B*TOPK

    const int chunk = (N + NB - 1) / NB;

    k_norm_q<<<B, 64, 0, stream>>>(q, qn);
    k_cand<<<NB, 256, 0, stream>>>(keys, qn, cand_s, cand_i, N, chunk);
    k_merge<<<B, 64, 0, stream>>>(cand_s, cand_i, values, out_slots, out_scores);
}